// Round 2
// baseline (256.268 us; speedup 1.0000x reference)
//
#include <hip/hip_runtime.h>
#include <hip/hip_bf16.h>
#include <cstdint>
#include <cstddef>

#define B_SZ 4096
#define K_NB 64

typedef __attribute__((ext_vector_type(4))) float f32x4;
typedef __attribute__((ext_vector_type(2))) float f32x2;
typedef __attribute__((ext_vector_type(8))) short sv8;
typedef __attribute__((ext_vector_type(8))) __bf16 bfv8;

static __device__ __forceinline__ short f2bf(float x) {
  union { float f; unsigned u; } v; v.f = x;
  unsigned r = v.u + 0x7fffu + ((v.u >> 16) & 1u);
  return (short)(r >> 16);
}

static __device__ __forceinline__ f32x4 MFMA(sv8 a, sv8 b, f32x4 c) {
  return __builtin_amdgcn_mfma_f32_16x16x32_bf16(
      __builtin_bit_cast(bfv8, a), __builtin_bit_cast(bfv8, b), c, 0, 0, 0);
}

static __device__ __forceinline__ float fast_sigmoid(float x) {
  return __builtin_amdgcn_rcpf(1.f + __expf(-x));
}
static __device__ __forceinline__ float fast_tanh(float x) {
  const float e = __expf(2.f * x);
  return 1.f - 2.f * __builtin_amdgcn_rcpf(e + 1.f);
}

// ---------------------------------------------------------------------------
// Phase A: one block per (b, layer). Gathers h/r/tl rows, fused attention
// logit, softmax(sigmoid(.)), 2-step RNN via bf16 MFMA, pi-weighted sum.
// Writes opart[layer][b][64] f32.
// ---------------------------------------------------------------------------
__global__ __launch_bounds__(256) void ncfg_neigh(
    const int* __restrict__ heads, const int* __restrict__ rels,
    const int* __restrict__ tails, const float* __restrict__ emb,
    const float* __restrict__ trf, const float* __restrict__ attn_w,
    const float* __restrict__ attn_b, const float* __restrict__ W_ih,
    const float* __restrict__ W_hh, const float* __restrict__ b_ih,
    const float* __restrict__ b_hh, float* __restrict__ opart) {
  const int bid = blockIdx.x;
  const int layer = bid >> 12;          // grid = 2*4096
  const int b = bid & (B_SZ - 1);
  const int t = threadIdx.x;
  const int lane = t & 63;
  const int w = t >> 6;                 // wave 0..3, owns rows w*16..w*16+15
  const int fr = lane & 15;
  const int fg = lane >> 4;
  const int j2 = lane & 31;
  const int half = lane >> 5;

  // 64x64 bf16 tiles, row stride 72 shorts (144 B) to break bank conflicts
  __shared__ __align__(16) short h_bf[64 * 72];
  __shared__ __align__(16) short tl_bf[64 * 72];
  __shared__ __align__(16) short h1_bf[64 * 72];
  __shared__ float logits[64];
  __shared__ float pi_s[64];
  __shared__ float o_lds[4][64];
  __shared__ int idx_h[64], idx_t[64], idx_r[64];

  const size_t ibase = ((size_t)layer * B_SZ + b) * K_NB;
  if (t < 64) idx_h[t] = heads[ibase + t];
  else if (t < 128) idx_t[t - 64] = tails[ibase + (t - 64)];
  else if (t < 192) idx_r[t - 128] = rels[ibase + (t - 128)];
  __syncthreads();

  // attention weight slices for this lane's two feature columns
  const f32x2 awh = *(const f32x2*)(attn_w + 2 * j2);
  const f32x2 awr = *(const f32x2*)(attn_w + 64 + 2 * j2);
  const f32x2 awt = *(const f32x2*)(attn_w + 128 + 2 * j2);

  // gather + attention logit + bf16 staging (2 rows per wave-iteration)
  #pragma unroll
  for (int it = 0; it < 8; ++it) {
    const int row = (w << 4) + (it << 1) + half;
    const int hi = idx_h[row], ti = idx_t[row], ri = idx_r[row];
    const f32x2 hv = *(const f32x2*)(emb + (size_t)hi * 64 + 2 * j2);
    const f32x2 tv = *(const f32x2*)(emb + (size_t)ti * 64 + 2 * j2);
    const f32x2 rv = *(const f32x2*)(trf + ri * 64 + 2 * j2);
    float ap = hv.x * awh.x + hv.y * awh.y + rv.x * awr.x + rv.y * awr.y +
               tv.x * awt.x + tv.y * awt.y;
    #pragma unroll
    for (int m = 1; m < 32; m <<= 1) ap += __shfl_xor(ap, m);
    if (j2 == 0) logits[row] = ap;
    const unsigned ph = (unsigned)(unsigned short)f2bf(hv.x) |
                        ((unsigned)(unsigned short)f2bf(hv.y) << 16);
    const unsigned pt = (unsigned)(unsigned short)f2bf(tv.x) |
                        ((unsigned)(unsigned short)f2bf(tv.y) << 16);
    *(unsigned*)&h_bf[row * 72 + 2 * j2] = ph;
    *(unsigned*)&tl_bf[row * 72 + 2 * j2] = pt;
  }

  // B-operand fragments: lane holds W[nt*16+fr][kh*32+fg*8 .. +7] (L1/L2 hit)
  sv8 wih[8], whh[8];
  #pragma unroll
  for (int nt = 0; nt < 4; ++nt) {
    #pragma unroll
    for (int kh = 0; kh < 2; ++kh) {
      const int off = (nt * 16 + fr) * 64 + kh * 32 + fg * 8;
      f32x4 a0 = *(const f32x4*)(W_ih + off);
      f32x4 a1 = *(const f32x4*)(W_ih + off + 4);
      sv8 f;
      f[0] = f2bf(a0.x); f[1] = f2bf(a0.y); f[2] = f2bf(a0.z); f[3] = f2bf(a0.w);
      f[4] = f2bf(a1.x); f[5] = f2bf(a1.y); f[6] = f2bf(a1.z); f[7] = f2bf(a1.w);
      wih[nt * 2 + kh] = f;
      a0 = *(const f32x4*)(W_hh + off);
      a1 = *(const f32x4*)(W_hh + off + 4);
      f[0] = f2bf(a0.x); f[1] = f2bf(a0.y); f[2] = f2bf(a0.z); f[3] = f2bf(a0.w);
      f[4] = f2bf(a1.x); f[5] = f2bf(a1.y); f[6] = f2bf(a1.z); f[7] = f2bf(a1.w);
      whh[nt * 2 + kh] = f;
    }
  }
  float bsum[4];
  #pragma unroll
  for (int nt = 0; nt < 4; ++nt)
    bsum[nt] = b_ih[nt * 16 + fr] + b_hh[nt * 16 + fr];

  __syncthreads();  // all logits visible

  if (w == 0) {  // sigmoid then softmax over the 64 neighbors
    const float x = logits[lane] + attn_b[0];
    const float s = fast_sigmoid(x);
    float mx = s;
    #pragma unroll
    for (int m = 1; m < 64; m <<= 1) mx = fmaxf(mx, __shfl_xor(mx, m));
    const float e = __expf(s - mx);
    float sm = e;
    #pragma unroll
    for (int m = 1; m < 64; m <<= 1) sm += __shfl_xor(sm, m);
    pi_s[lane] = e * __builtin_amdgcn_rcpf(sm);
  }

  const f32x4 zz = {0.f, 0.f, 0.f, 0.f};
  const int arow = ((w << 4) + fr) * 72;

  // GEMM1: h1 = tanh(H @ W_ih^T + b_ih + b_hh)
  f32x4 acc[4] = {zz, zz, zz, zz};
  #pragma unroll
  for (int kh = 0; kh < 2; ++kh) {
    const sv8 a = *(const sv8*)&h_bf[arow + kh * 32 + fg * 8];
    #pragma unroll
    for (int nt = 0; nt < 4; ++nt) acc[nt] = MFMA(a, wih[nt * 2 + kh], acc[nt]);
  }
  #pragma unroll
  for (int nt = 0; nt < 4; ++nt) {
    #pragma unroll
    for (int r = 0; r < 4; ++r) {
      const float h1v = fast_tanh(acc[nt][r] + bsum[nt]);
      h1_bf[((w << 4) + (fg << 2) + r) * 72 + nt * 16 + fr] = f2bf(h1v);
    }
  }

  // GEMM2+3: h2pre = TL @ W_ih^T + H1 @ W_hh^T   (same-wave LDS dependency)
  f32x4 acc2[4] = {zz, zz, zz, zz};
  #pragma unroll
  for (int kh = 0; kh < 2; ++kh) {
    const sv8 a = *(const sv8*)&tl_bf[arow + kh * 32 + fg * 8];
    #pragma unroll
    for (int nt = 0; nt < 4; ++nt) acc2[nt] = MFMA(a, wih[nt * 2 + kh], acc2[nt]);
  }
  #pragma unroll
  for (int kh = 0; kh < 2; ++kh) {
    const sv8 a = *(const sv8*)&h1_bf[arow + kh * 32 + fg * 8];
    #pragma unroll
    for (int nt = 0; nt < 4; ++nt) acc2[nt] = MFMA(a, whh[nt * 2 + kh], acc2[nt]);
  }

  __syncthreads();  // pi_s ready

  // weighted sum over neighbors: o[i] += pi[k] * tanh(h2pre + bsum)
  const f32x4 piv = *(const f32x4*)&pi_s[(w << 4) + (fg << 2)];
  #pragma unroll
  for (int nt = 0; nt < 4; ++nt) {
    float s = piv.x * fast_tanh(acc2[nt][0] + bsum[nt]) +
              piv.y * fast_tanh(acc2[nt][1] + bsum[nt]) +
              piv.z * fast_tanh(acc2[nt][2] + bsum[nt]) +
              piv.w * fast_tanh(acc2[nt][3] + bsum[nt]);
    s += __shfl_xor(s, 16);
    s += __shfl_xor(s, 32);
    if (lane < 16) o_lds[w][nt * 16 + fr] = s;
  }
  __syncthreads();
  if (w == 0) {
    const float o =
        o_lds[0][lane] + o_lds[1][lane] + o_lds[2][lane] + o_lds[3][lane];
    opart[((size_t)layer * B_SZ + b) * 64 + lane] = o;
  }
}

// ---------------------------------------------------------------------------
// Phase B: NCF head. 4 batch rows per block (1 wave each).
// ---------------------------------------------------------------------------
__global__ __launch_bounds__(256) void ncfg_head(
    const float* __restrict__ opart, const float* __restrict__ emb,
    const int* __restrict__ items, const float* __restrict__ l1_w,
    const float* __restrict__ l1_b, const float* __restrict__ l2_w,
    const float* __restrict__ l2_b, const float* __restrict__ l3_w,
    const float* __restrict__ l3_b, const float* __restrict__ lin_w,
    const float* __restrict__ lin_b, float* __restrict__ out) {
  const int wv = threadIdx.x >> 6;
  const int i = threadIdx.x & 63;
  const int b = blockIdx.x * 4 + wv;

  __shared__ float ui[4][128];
  __shared__ float yy[4][64];

  const float ue = opart[(size_t)b * 64 + i] +
                   opart[((size_t)B_SZ + b) * 64 + i];
  const float ie = emb[(size_t)items[b] * 64 + i];
  ui[wv][i] = ue;
  ui[wv][64 + i] = ie;
  __syncthreads();

  float acc = l1_b[i];
  {
    const float* wr = l1_w + i * 128;
    #pragma unroll
    for (int j = 0; j < 128; j += 4) {
      const f32x4 wvv = *(const f32x4*)(wr + j);
      const f32x4 uv = *(const f32x4*)&ui[wv][j];
      acc += wvv.x * uv.x + wvv.y * uv.y + wvv.z * uv.z + wvv.w * uv.w;
    }
  }
  float y = fmaxf(acc, 0.f);
  yy[wv][i] = y;
  __syncthreads();

  acc = l2_b[i];
  {
    const float* wr = l2_w + i * 64;
    #pragma unroll
    for (int j = 0; j < 64; j += 4) {
      const f32x4 wvv = *(const f32x4*)(wr + j);
      const f32x4 uv = *(const f32x4*)&yy[wv][j];
      acc += wvv.x * uv.x + wvv.y * uv.y + wvv.z * uv.z + wvv.w * uv.w;
    }
  }
  y = fmaxf(acc, 0.f);
  __syncthreads();
  yy[wv][i] = y;
  __syncthreads();

  acc = l3_b[i];
  {
    const float* wr = l3_w + i * 64;
    #pragma unroll
    for (int j = 0; j < 64; j += 4) {
      const f32x4 wvv = *(const f32x4*)(wr + j);
      const f32x4 uv = *(const f32x4*)&yy[wv][j];
      acc += wvv.x * uv.x + wvv.y * uv.y + wvv.z * uv.z + wvv.w * uv.w;
    }
  }
  const float y1 = fast_sigmoid(acc);
  const float y2 = ue * ie;

  float part = y1 * lin_w[i] + y2 * lin_w[64 + i];
  #pragma unroll
  for (int m = 1; m < 64; m <<= 1) part += __shfl_xor(part, m);
  if (i == 0) out[b] = fast_sigmoid(part + lin_b[0]);
}

extern "C" void kernel_launch(void* const* d_in, const int* in_sizes, int n_in,
                              void* d_out, int out_size, void* d_ws,
                              size_t ws_size, hipStream_t stream) {
  (void)in_sizes; (void)n_in; (void)out_size; (void)ws_size;
  const int* items = (const int*)d_in[0];
  const int* heads = (const int*)d_in[1];
  const int* rels = (const int*)d_in[2];
  const int* tails = (const int*)d_in[3];
  const float* emb = (const float*)d_in[4];
  const float* trf = (const float*)d_in[5];
  const float* attn_w = (const float*)d_in[6];
  const float* attn_b = (const float*)d_in[7];
  const float* W_ih = (const float*)d_in[8];
  const float* W_hh = (const float*)d_in[9];
  const float* b_ih = (const float*)d_in[10];
  const float* b_hh = (const float*)d_in[11];
  const float* l1_w = (const float*)d_in[12];
  const float* l1_b = (const float*)d_in[13];
  const float* l2_w = (const float*)d_in[14];
  const float* l2_b = (const float*)d_in[15];
  const float* l3_w = (const float*)d_in[16];
  const float* l3_b = (const float*)d_in[17];
  const float* lin_w = (const float*)d_in[18];
  const float* lin_b = (const float*)d_in[19];
  float* out = (float*)d_out;
  float* opart = (float*)d_ws;  // [L=2][B=4096][64] f32 = 2 MB

  ncfg_neigh<<<dim3(2 * B_SZ), dim3(256), 0, stream>>>(
      heads, rels, tails, emb, trf, attn_w, attn_b, W_ih, W_hh, b_ih, b_hh,
      opart);
  ncfg_head<<<dim3(B_SZ / 4), dim3(256), 0, stream>>>(
      opart, emb, items, l1_w, l1_b, l2_w, l2_b, l3_w, l3_b, lin_w, lin_b,
      out);
}

// Round 3
// 103.102 us; speedup vs baseline: 2.4856x; 2.4856x over previous
//
#include <hip/hip_runtime.h>
#include <hip/hip_bf16.h>
#include <cstdint>
#include <cstddef>

#define B_SZ 4096
#define STRIDE 72

typedef __attribute__((ext_vector_type(4))) float f32x4;
typedef __attribute__((ext_vector_type(8))) short sv8;
typedef __attribute__((ext_vector_type(8))) __bf16 bfv8;

// Pre-packed parameters (written by ncfg_prep each launch, read by ncfg_neigh)
__device__ __align__(16) short g_wf[2][8][64][8];  // [mat][frag nt*2+kh][lane][j]
__device__ float g_bsum[64];                       // b_ih + b_hh
__device__ float g_reldot[32];                     // trf[r] . attn_w[64:128]

static __device__ __forceinline__ short f2bf(float x) {
  union { float f; unsigned u; } v; v.f = x;
  unsigned r = v.u + 0x7fffu + ((v.u >> 16) & 1u);
  return (short)(r >> 16);
}

static __device__ __forceinline__ f32x4 MFMA(sv8 a, sv8 b, f32x4 c) {
  return __builtin_amdgcn_mfma_f32_16x16x32_bf16(
      __builtin_bit_cast(bfv8, a), __builtin_bit_cast(bfv8, b), c, 0, 0, 0);
}

static __device__ __forceinline__ float fast_sigmoid(float x) {
  return __builtin_amdgcn_rcpf(1.f + __expf(-x));
}
static __device__ __forceinline__ float fast_tanh(float x) {
  const float e = __expf(2.f * x);
  return 1.f - 2.f * __builtin_amdgcn_rcpf(e + 1.f);
}
static __device__ __forceinline__ float dot4(f32x4 a, f32x4 b) {
  return a.x * b.x + a.y * b.y + a.z * b.z + a.w * b.w;
}
static __device__ __forceinline__ sv8 pack8(f32x4 a, f32x4 b) {
  sv8 f;
  f[0] = f2bf(a.x); f[1] = f2bf(a.y); f[2] = f2bf(a.z); f[3] = f2bf(a.w);
  f[4] = f2bf(b.x); f[5] = f2bf(b.y); f[6] = f2bf(b.z); f[7] = f2bf(b.w);
  return f;
}

// ---------------------------------------------------------------------------
// Prep: pack W into bf16 MFMA fragments, fold biases, precompute rel dots.
// ---------------------------------------------------------------------------
__global__ __launch_bounds__(256) void ncfg_prep(
    const float* __restrict__ W_ih, const float* __restrict__ W_hh,
    const float* __restrict__ b_ih, const float* __restrict__ b_hh,
    const float* __restrict__ trf, const float* __restrict__ attn_w) {
  const int t = threadIdx.x;
  for (int q = t; q < 1024; q += 256) {
    const int m = q >> 9, f = (q >> 6) & 7, ln = q & 63;
    const int nt = f >> 1, kh = f & 1, fr = ln & 15, fg = ln >> 4;
    const float* W = m ? W_hh : W_ih;
    const float* src = W + (nt * 16 + fr) * 64 + kh * 32 + fg * 8;
    short* dst = &g_wf[m][f][ln][0];
    #pragma unroll
    for (int j = 0; j < 8; ++j) dst[j] = f2bf(src[j]);
  }
  if (t < 64) g_bsum[t] = b_ih[t] + b_hh[t];
  if (t < 32) {
    float s = 0.f;
    #pragma unroll 8
    for (int c = 0; c < 64; ++c) s += trf[t * 64 + c] * attn_w[64 + c];
    g_reldot[t] = s;
  }
}

// ---------------------------------------------------------------------------
// Phase A: one block per (b, layer). Register-direct gathers in fragment
// layout, fused attention logit, softmax(sigmoid), 2-step RNN via bf16 MFMA.
// ---------------------------------------------------------------------------
__global__ __launch_bounds__(256, 4) void ncfg_neigh(
    const int* __restrict__ heads, const int* __restrict__ rels,
    const int* __restrict__ tails, const float* __restrict__ emb,
    const float* __restrict__ attn_w, const float* __restrict__ attn_b,
    float* __restrict__ opart) {
  const int bid = blockIdx.x;
  const int layer = bid >> 12;  // grid = 2*4096
  const int b = bid & (B_SZ - 1);
  const int t = threadIdx.x;
  const int lane = t & 63;
  const int w = t >> 6;         // wave 0..3 owns rows w*16..w*16+15
  const int fr = lane & 15;
  const int fg = lane >> 4;

  __shared__ __align__(16) short h1_bf[64 * STRIDE];
  __shared__ float logits[64];
  __shared__ float pi_s[64];
  __shared__ float o_lds[4][64];

  const int row = (w << 4) + fr;
  const size_t ibase = ((size_t)layer * B_SZ + b) * 64;
  const int hi = heads[ibase + row];
  const int ti = tails[ibase + row];
  const int ri = rels[ibase + row];

  // 8 independent HBM gathers, directly in A-fragment layout
  const float* hrow = emb + (size_t)hi * 64;
  const float* trow = emb + (size_t)ti * 64;
  const int c0 = fg * 8;
  const f32x4 h0a = *(const f32x4*)(hrow + c0);
  const f32x4 h0b = *(const f32x4*)(hrow + c0 + 4);
  const f32x4 h1a = *(const f32x4*)(hrow + 32 + c0);
  const f32x4 h1b = *(const f32x4*)(hrow + 32 + c0 + 4);
  const f32x4 t0a = *(const f32x4*)(trow + c0);
  const f32x4 t0b = *(const f32x4*)(trow + c0 + 4);
  const f32x4 t1a = *(const f32x4*)(trow + 32 + c0);
  const f32x4 t1b = *(const f32x4*)(trow + 32 + c0 + 4);

  // W_ih fragments (L2-hot packed bf16) + fused bias
  sv8 wih[8];
  #pragma unroll
  for (int f = 0; f < 8; ++f) wih[f] = *(const sv8*)&g_wf[0][f][lane][0];
  float bsum[4];
  #pragma unroll
  for (int nt = 0; nt < 4; ++nt) bsum[nt] = g_bsum[nt * 16 + fr];

  // attention logit: per-lane partial over this lane's 16 cols of h and tl
  const f32x4 ah0a = *(const f32x4*)(attn_w + c0);
  const f32x4 ah0b = *(const f32x4*)(attn_w + c0 + 4);
  const f32x4 ah1a = *(const f32x4*)(attn_w + 32 + c0);
  const f32x4 ah1b = *(const f32x4*)(attn_w + 32 + c0 + 4);
  const f32x4 at0a = *(const f32x4*)(attn_w + 128 + c0);
  const f32x4 at0b = *(const f32x4*)(attn_w + 128 + c0 + 4);
  const f32x4 at1a = *(const f32x4*)(attn_w + 160 + c0);
  const f32x4 at1b = *(const f32x4*)(attn_w + 160 + c0 + 4);
  float ap = dot4(h0a, ah0a) + dot4(h0b, ah0b) + dot4(h1a, ah1a) +
             dot4(h1b, ah1b) + dot4(t0a, at0a) + dot4(t0b, at0b) +
             dot4(t1a, at1a) + dot4(t1b, at1b);
  ap += __shfl_xor(ap, 16);
  ap += __shfl_xor(ap, 32);
  if (fg == 0) logits[row] = ap + g_reldot[ri];

  // bf16 A-fragments
  sv8 ha[2], ta[2];
  ha[0] = pack8(h0a, h0b);
  ha[1] = pack8(h1a, h1b);
  ta[0] = pack8(t0a, t0b);
  ta[1] = pack8(t1a, t1b);

  __syncthreads();  // logits visible

  if (w == 0) {  // sigmoid then softmax over 64 neighbors
    const float x = logits[lane] + attn_b[0];
    const float s = fast_sigmoid(x);
    float mx = s;
    #pragma unroll
    for (int m = 1; m < 64; m <<= 1) mx = fmaxf(mx, __shfl_xor(mx, m));
    const float e = __expf(s - mx);
    float sm = e;
    #pragma unroll
    for (int m = 1; m < 64; m <<= 1) sm += __shfl_xor(sm, m);
    pi_s[lane] = e * __builtin_amdgcn_rcpf(sm);
  }

  const f32x4 zz = {0.f, 0.f, 0.f, 0.f};

  // GEMM1: h1 = tanh(H @ W_ih^T + bsum)
  f32x4 acc[4] = {zz, zz, zz, zz};
  #pragma unroll
  for (int kh = 0; kh < 2; ++kh)
    #pragma unroll
    for (int nt = 0; nt < 4; ++nt) acc[nt] = MFMA(ha[kh], wih[nt * 2 + kh], acc[nt]);

  // W_hh fragments (latency hides under tanh + GEMM2a)
  sv8 whh[8];
  #pragma unroll
  for (int f = 0; f < 8; ++f) whh[f] = *(const sv8*)&g_wf[1][f][lane][0];

  #pragma unroll
  for (int nt = 0; nt < 4; ++nt)
    #pragma unroll
    for (int r = 0; r < 4; ++r)
      h1_bf[((w << 4) + (fg << 2) + r) * STRIDE + nt * 16 + fr] =
          f2bf(fast_tanh(acc[nt][r] + bsum[nt]));

  // GEMM2: h2pre = TL @ W_ih^T + H1 @ W_hh^T (h1 is same-wave LDS)
  f32x4 acc2[4] = {zz, zz, zz, zz};
  #pragma unroll
  for (int kh = 0; kh < 2; ++kh)
    #pragma unroll
    for (int nt = 0; nt < 4; ++nt) acc2[nt] = MFMA(ta[kh], wih[nt * 2 + kh], acc2[nt]);
  const int arow = ((w << 4) + fr) * STRIDE;
  #pragma unroll
  for (int kh = 0; kh < 2; ++kh) {
    const sv8 a = *(const sv8*)&h1_bf[arow + kh * 32 + fg * 8];
    #pragma unroll
    for (int nt = 0; nt < 4; ++nt) acc2[nt] = MFMA(a, whh[nt * 2 + kh], acc2[nt]);
  }

  __syncthreads();  // pi_s ready

  const f32x4 piv = *(const f32x4*)&pi_s[(w << 4) + (fg << 2)];
  #pragma unroll
  for (int nt = 0; nt < 4; ++nt) {
    float s = piv.x * fast_tanh(acc2[nt][0] + bsum[nt]) +
              piv.y * fast_tanh(acc2[nt][1] + bsum[nt]) +
              piv.z * fast_tanh(acc2[nt][2] + bsum[nt]) +
              piv.w * fast_tanh(acc2[nt][3] + bsum[nt]);
    s += __shfl_xor(s, 16);
    s += __shfl_xor(s, 32);
    if (lane < 16) o_lds[w][nt * 16 + fr] = s;
  }
  __syncthreads();
  if (w == 0) {
    const float o =
        o_lds[0][lane] + o_lds[1][lane] + o_lds[2][lane] + o_lds[3][lane];
    opart[((size_t)layer * B_SZ + b) * 64 + lane] = o;
  }
}

// ---------------------------------------------------------------------------
// Phase B: NCF head. 4 batch rows per block (1 wave each).
// ---------------------------------------------------------------------------
__global__ __launch_bounds__(256) void ncfg_head(
    const float* __restrict__ opart, const float* __restrict__ emb,
    const int* __restrict__ items, const float* __restrict__ l1_w,
    const float* __restrict__ l1_b, const float* __restrict__ l2_w,
    const float* __restrict__ l2_b, const float* __restrict__ l3_w,
    const float* __restrict__ l3_b, const float* __restrict__ lin_w,
    const float* __restrict__ lin_b, float* __restrict__ out) {
  const int wv = threadIdx.x >> 6;
  const int i = threadIdx.x & 63;
  const int b = blockIdx.x * 4 + wv;

  __shared__ float ui[4][128];
  __shared__ float yy[4][64];

  const float ue = opart[(size_t)b * 64 + i] +
                   opart[((size_t)B_SZ + b) * 64 + i];
  const float ie = emb[(size_t)items[b] * 64 + i];
  ui[wv][i] = ue;
  ui[wv][64 + i] = ie;
  __syncthreads();

  float acc = l1_b[i];
  {
    const float* wr = l1_w + i * 128;
    #pragma unroll
    for (int j = 0; j < 128; j += 4) {
      const f32x4 wvv = *(const f32x4*)(wr + j);
      const f32x4 uv = *(const f32x4*)&ui[wv][j];
      acc += wvv.x * uv.x + wvv.y * uv.y + wvv.z * uv.z + wvv.w * uv.w;
    }
  }
  float y = fmaxf(acc, 0.f);
  yy[wv][i] = y;
  __syncthreads();

  acc = l2_b[i];
  {
    const float* wr = l2_w + i * 64;
    #pragma unroll
    for (int j = 0; j < 64; j += 4) {
      const f32x4 wvv = *(const f32x4*)(wr + j);
      const f32x4 uv = *(const f32x4*)&yy[wv][j];
      acc += wvv.x * uv.x + wvv.y * uv.y + wvv.z * uv.z + wvv.w * uv.w;
    }
  }
  y = fmaxf(acc, 0.f);
  __syncthreads();
  yy[wv][i] = y;
  __syncthreads();

  acc = l3_b[i];
  {
    const float* wr = l3_w + i * 64;
    #pragma unroll
    for (int j = 0; j < 64; j += 4) {
      const f32x4 wvv = *(const f32x4*)(wr + j);
      const f32x4 uv = *(const f32x4*)&yy[wv][j];
      acc += wvv.x * uv.x + wvv.y * uv.y + wvv.z * uv.z + wvv.w * uv.w;
    }
  }
  const float y1 = fast_sigmoid(acc);
  const float y2 = ue * ie;

  float part = y1 * lin_w[i] + y2 * lin_w[64 + i];
  #pragma unroll
  for (int m = 1; m < 64; m <<= 1) part += __shfl_xor(part, m);
  if (i == 0) out[b] = fast_sigmoid(part + lin_b[0]);
}

extern "C" void kernel_launch(void* const* d_in, const int* in_sizes, int n_in,
                              void* d_out, int out_size, void* d_ws,
                              size_t ws_size, hipStream_t stream) {
  (void)in_sizes; (void)n_in; (void)out_size; (void)ws_size;
  const int* items = (const int*)d_in[0];
  const int* heads = (const int*)d_in[1];
  const int* rels = (const int*)d_in[2];
  const int* tails = (const int*)d_in[3];
  const float* emb = (const float*)d_in[4];
  const float* trf = (const float*)d_in[5];
  const float* attn_w = (const float*)d_in[6];
  const float* attn_b = (const float*)d_in[7];
  const float* W_ih = (const float*)d_in[8];
  const float* W_hh = (const float*)d_in[9];
  const float* b_ih = (const float*)d_in[10];
  const float* b_hh = (const float*)d_in[11];
  const float* l1_w = (const float*)d_in[12];
  const float* l1_b = (const float*)d_in[13];
  const float* l2_w = (const float*)d_in[14];
  const float* l2_b = (const float*)d_in[15];
  const float* l3_w = (const float*)d_in[16];
  const float* l3_b = (const float*)d_in[17];
  const float* lin_w = (const float*)d_in[18];
  const float* lin_b = (const float*)d_in[19];
  float* out = (float*)d_out;
  float* opart = (float*)d_ws;  // [L=2][B=4096][64] f32 = 2 MB

  ncfg_prep<<<dim3(1), dim3(256), 0, stream>>>(W_ih, W_hh, b_ih, b_hh, trf,
                                               attn_w);
  ncfg_neigh<<<dim3(2 * B_SZ), dim3(256), 0, stream>>>(
      heads, rels, tails, emb, attn_w, attn_b, opart);
  ncfg_head<<<dim3(B_SZ / 4), dim3(256), 0, stream>>>(
      opart, emb, items, l1_w, l1_b, l2_w, l2_b, l3_w, l3_b, lin_w, lin_b,
      out);
}